// Round 2
// baseline (435.234 us; speedup 1.0000x reference)
//
#include <hip/hip_runtime.h>
#include <cstdint>
#include <cstddef>

#define S_DIM 1024
#define NPTS (S_DIM * S_DIM)
#define NLEV 16
#define TBL (1u << 19)
#define TMASK (TBL - 1u)
#define PRIME_Y 2654435761u

typedef float v4f __attribute__((ext_vector_type(4)));
typedef short v8s __attribute__((ext_vector_type(8)));

// ---- split-bf16 helpers: x = hi + lo, both truncated bf16 ----
// pack two fp32 (a=even k, b=odd k) into one dword of 2 bf16 (a in low short).
__device__ __forceinline__ void split2(float a, float b, uint32_t& hi, uint32_t& lo) {
    uint32_t ua = __float_as_uint(a), ub = __float_as_uint(b);
    uint32_t ha = ua & 0xFFFF0000u, hb = ub & 0xFFFF0000u;
    float la = a - __uint_as_float(ha);
    float lb = b - __uint_as_float(hb);
    hi = (ha >> 16) | hb;
    lo = (__float_as_uint(la) >> 16) | (__float_as_uint(lb) & 0xFFFF0000u);
}

// ============================================================================
// Pre-pass: build bf16 hi/lo A-fragments of W0^T (64x32) and W1^T (64x64) in
// d_ws, fragment-linear so the main kernel loads each lane's 16B with one
// coalesced uint4 load.  A-frag (16x16x32): lane holds A[m=lane&15][k=q*8+j].
// ws as uint4: [0,256) W0hi | [256,512) W0lo | [512,1024) W1hi | [1024,1536) W1lo
// ============================================================================
__global__ __launch_bounds__(256) void prep_weights(const float* __restrict__ W0,
                                                    const float* __restrict__ W1,
                                                    uint4* __restrict__ ws) {
    const int tid = threadIdx.x;          // 0..255
    const int lane = tid & 63;
    const int m = lane & 15, q = lane >> 4;

    {   // W0^T: 4 n-tiles, 1 k-step. unit = tile*64+lane = tid.
        const int tile = tid >> 6;
        const int n = tile * 16 + m;
        uint32_t hi[4], lo[4];
        #pragma unroll
        for (int d = 0; d < 4; ++d) {
            const int k0 = q * 8 + 2 * d;
            split2(W0[k0 * 64 + n], W0[(k0 + 1) * 64 + n], hi[d], lo[d]);
        }
        ws[tid]       = make_uint4(hi[0], hi[1], hi[2], hi[3]);
        ws[256 + tid] = make_uint4(lo[0], lo[1], lo[2], lo[3]);
    }

    #pragma unroll
    for (int rep = 0; rep < 2; ++rep) {   // W1^T: 8 frags (nt*2+ks) x 64 lanes
        const int unit = tid + rep * 256;     // 0..511
        const int l2 = unit & 63, frag = unit >> 6;
        const int nt = frag >> 1, ks = frag & 1;
        const int mm = l2 & 15, qq = l2 >> 4;
        const int n = nt * 16 + mm;
        uint32_t hi[4], lo[4];
        #pragma unroll
        for (int d = 0; d < 4; ++d) {
            const int k0 = ks * 32 + qq * 8 + 2 * d;
            split2(W1[k0 * 64 + n], W1[(k0 + 1) * 64 + n], hi[d], lo[d]);
        }
        ws[512 + unit]  = make_uint4(hi[0], hi[1], hi[2], hi[3]);
        ws[1024 + unit] = make_uint4(lo[0], lo[1], lo[2], lo[3]);
    }
}

// ---- per-level hash-grid feature (unchanged, verified) ----
static __device__ __forceinline__ float2 level_feat(float x, float y, int res,
                                                    const float* __restrict__ tb) {
    const float fr = (float)res;
    const float px = x * fr, py = y * fr;
    const float fx = floorf(px), fy = floorf(py);
    const float wx = px - fx, wy = py - fy;
    const int x0 = (int)fx, y0 = (int)fy;

    int i00, i01, i10, i11;
    const bool dense = ((long long)(res + 1) * (long long)(res + 1) <= (long long)TBL);
    if (dense) {
        const int st = res + 1;
        i00 = x0 + y0 * st;
        i01 = i00 + st;
        i10 = i00 + 1;
        i11 = i01 + 1;
    } else {
        const unsigned a = (unsigned)x0, b = (unsigned)y0;
        const unsigned hb0 = b * PRIME_Y;
        const unsigned hb1 = (b + 1u) * PRIME_Y;
        i00 = (int)((a ^ hb0) & TMASK);
        i01 = (int)((a ^ hb1) & TMASK);
        i10 = (int)(((a + 1u) ^ hb0) & TMASK);
        i11 = (int)(((a + 1u) ^ hb1) & TMASK);
    }

    const float2 f00 = *(const float2*)(tb + 2 * (size_t)i00);
    const float2 f01 = *(const float2*)(tb + 2 * (size_t)i01);
    const float2 f10 = *(const float2*)(tb + 2 * (size_t)i10);
    const float2 f11 = *(const float2*)(tb + 2 * (size_t)i11);

    const float omx = 1.f - wx, omy = 1.f - wy;
    const float w00 = omx * omy, w01 = omx * wy, w10 = wx * omy, w11 = wx * wy;

    float2 e;
    e.x = f00.x * w00 + f01.x * w01 + f10.x * w10 + f11.x * w11;
    e.y = f00.y * w00 + f01.y * w01 + f10.y * w10 + f11.y * w11;
    return e;
}

// ============================================================================
// Main kernel. Block = 256 = 4 waves; each wave owns 64 points (4 M-tiles).
// Per M-tile (fused, #pragma unroll 1 to bound register pressure):
//   TRANSPOSED encode: lane (m,q) encodes levels 4q..4q+3 of point t*16+m ->
//     results land directly in MFMA B-frag layout (no enc LDS, no transpose).
//   L0 MFMA (A=W0^T frags in regs), relu+split via wave-local LDS bounce,
//   L1 MFMA (A=W1^T frags from LDS), L2 (64->3) in VALU + shfl_xor reduce.
// Only ONE tile's eH/eL (8 VGPRs) live at a time -> no scratch spill
// (round-1 lesson: 4-tile eH/eL + full unroll spilled 437 MB to scratch).
// LDS: h0 bounce 17408 + W1 frags 16384 + w2t 768 + res 64 = 34.6 KB
//   -> 4 blocks/CU, 16 waves/CU; VGPR capped at 128 by launch_bounds.
// ============================================================================
__global__ __launch_bounds__(256, 4) void ngp_mfma(
    const float* __restrict__ xy,
    const float* __restrict__ tables,
    const float* __restrict__ W2,
    const uint4* __restrict__ ws,
    float* __restrict__ out)
{
    // h0 rows: per wave 16 points x (64 hi | 64 lo) = 256B, padded to 272B
    __shared__ alignas(16) uint32_t h0LDS[4 * 16 * 68];      // 17408 B
    // W1^T fragments: [0,512) hi, [512,1024) lo, lane-linear 16B units
    __shared__ alignas(16) uint4 w1LDS[1024];                // 16384 B
    // W2 transposed: w2t[c][n], c<3, n<64 -> 16B-aligned 4-float reads
    __shared__ alignas(16) float w2t[3 * 64];                //   768 B
    __shared__ alignas(16) int resLDS[16];                   //    64 B

    const int tid = threadIdx.x;
    const int lane = tid & 63;
    const int wave = tid >> 6;
    const int m = lane & 15, q = lane >> 4;
    const int blockBase = blockIdx.x * 256;

    if (tid < 192) w2t[(tid % 3) * 64 + (tid / 3)] = W2[tid];
    if (tid < 16) {
        constexpr int RES[NLEV] = {16, 24, 36, 54, 81, 121, 182, 273,
                                   410, 615, 922, 1383, 2075, 3113, 4670, 7006};
        resLDS[tid] = RES[tid];
    }
    // stage W1 frags global->LDS (1024 uint4, 4 per thread)
    #pragma unroll
    for (int i = 0; i < 4; ++i) w1LDS[tid + 256 * i] = ws[512 + tid + 256 * i];

    // W0 frags stay in registers (32 VGPRs, reused by all 4 tiles)
    v8s w0h[4], w0l[4];
    #pragma unroll
    for (int tt = 0; tt < 4; ++tt) {
        w0h[tt] = __builtin_bit_cast(v8s, ws[tt * 64 + lane]);
        w0l[tt] = __builtin_bit_cast(v8s, ws[256 + tt * 64 + lane]);
    }

    __syncthreads();   // w2t / resLDS / w1LDS visibility

    // per-q level slice: levels 4q..4q+3 -> enc dims k = 8q..8q+7
    const int4 rq = *((const int4*)(resLDS + 4 * q));
    const float* tb0 = tables + (size_t)(4 * q) * (size_t)(TBL * 2u);
    const int rr[4] = {rq.x, rq.y, rq.z, rq.w};

    uint32_t* hrow = h0LDS + (wave * 16 + m) * 68;

    // ---------------- fused per-tile loop: encode -> L0 -> L1 -> L2 --------
    #pragma unroll 1
    for (int t = 0; t < 4; ++t) {
        // ---- transposed encode: this tile's B-frag directly in registers --
        const int pid = blockBase + wave * 64 + t * 16 + m;
        const float2 p = ((const float2*)xy)[pid];
        float ef[8];
        #pragma unroll
        for (int i = 0; i < 4; ++i) {
            const float2 e = level_feat(p.x, p.y, rr[i],
                                        tb0 + (size_t)i * (size_t)(TBL * 2u));
            ef[2 * i]     = e.x;
            ef[2 * i + 1] = e.y;
        }
        uint32_t hi[4], lo[4];
        #pragma unroll
        for (int d = 0; d < 4; ++d) split2(ef[2 * d], ef[2 * d + 1], hi[d], lo[d]);
        const v8s eH = __builtin_bit_cast(v8s, make_uint4(hi[0], hi[1], hi[2], hi[3]));
        const v8s eL = __builtin_bit_cast(v8s, make_uint4(lo[0], lo[1], lo[2], lo[3]));

        // ---- L0: D0[n][p] = W0^T x enc^T, 3-term split ----
        v4f acc0[4];
        #pragma unroll
        for (int nt = 0; nt < 4; ++nt) {
            v4f c = {0.f, 0.f, 0.f, 0.f};
            c = __builtin_amdgcn_mfma_f32_16x16x32_bf16(w0l[nt], eH, c, 0, 0, 0);
            c = __builtin_amdgcn_mfma_f32_16x16x32_bf16(w0h[nt], eL, c, 0, 0, 0);
            c = __builtin_amdgcn_mfma_f32_16x16x32_bf16(w0h[nt], eH, c, 0, 0, 0);
            acc0[nt] = c;
        }

        // ---- relu + split h0 -> wave-local LDS bounce (C-layout -> B-layout)
        // lane holds h0[n = nt*16 + q*4 + r][p = m]
        #pragma unroll
        for (int nt = 0; nt < 4; ++nt) {
            const float r0 = fmaxf(acc0[nt][0], 0.f), r1 = fmaxf(acc0[nt][1], 0.f);
            const float r2 = fmaxf(acc0[nt][2], 0.f), r3 = fmaxf(acc0[nt][3], 0.f);
            uint32_t h0w, l0w, h1w, l1w;
            split2(r0, r1, h0w, l0w);
            split2(r2, r3, h1w, l1w);
            *((uint2*)(hrow + nt * 8 + q * 2))      = make_uint2(h0w, h1w);
            *((uint2*)(hrow + 32 + nt * 8 + q * 2)) = make_uint2(l0w, l1w);
        }

        // ---- L1 B-frags (k = ks*32 + q*8 + j for point m) ----
        const v8s b0H = __builtin_bit_cast(v8s, *((const uint4*)(hrow + q * 4)));
        const v8s b0L = __builtin_bit_cast(v8s, *((const uint4*)(hrow + 32 + q * 4)));
        const v8s b1H = __builtin_bit_cast(v8s, *((const uint4*)(hrow + 16 + q * 4)));
        const v8s b1L = __builtin_bit_cast(v8s, *((const uint4*)(hrow + 48 + q * 4)));

        // ---- L1: D1[n][p] = W1^T x h0^T, A-frags streamed from LDS ----
        v4f acc1[4];
        #pragma unroll
        for (int nt = 0; nt < 4; ++nt) {
            const v8s a0h = __builtin_bit_cast(v8s, w1LDS[(nt * 2 + 0) * 64 + lane]);
            const v8s a0l = __builtin_bit_cast(v8s, w1LDS[512 + (nt * 2 + 0) * 64 + lane]);
            const v8s a1h = __builtin_bit_cast(v8s, w1LDS[(nt * 2 + 1) * 64 + lane]);
            const v8s a1l = __builtin_bit_cast(v8s, w1LDS[512 + (nt * 2 + 1) * 64 + lane]);
            v4f c = {0.f, 0.f, 0.f, 0.f};
            c = __builtin_amdgcn_mfma_f32_16x16x32_bf16(a0l, b0H, c, 0, 0, 0);
            c = __builtin_amdgcn_mfma_f32_16x16x32_bf16(a0h, b0L, c, 0, 0, 0);
            c = __builtin_amdgcn_mfma_f32_16x16x32_bf16(a0h, b0H, c, 0, 0, 0);
            c = __builtin_amdgcn_mfma_f32_16x16x32_bf16(a1l, b1H, c, 0, 0, 0);
            c = __builtin_amdgcn_mfma_f32_16x16x32_bf16(a1h, b1L, c, 0, 0, 0);
            c = __builtin_amdgcn_mfma_f32_16x16x32_bf16(a1h, b1H, c, 0, 0, 0);
            acc1[nt] = c;
        }

        // ---- L2 (64->3) in VALU: lane sums its 16 n's, quad-reduce ----
        float o0 = 0.f, o1 = 0.f, o2 = 0.f;
        #pragma unroll
        for (int nt = 0; nt < 4; ++nt) {
            const int n = nt * 16 + q * 4;
            const float4 wa = *((const float4*)(w2t + 0 * 64 + n));
            const float4 wb = *((const float4*)(w2t + 1 * 64 + n));
            const float4 wc = *((const float4*)(w2t + 2 * 64 + n));
            const float h0r = fmaxf(acc1[nt][0], 0.f), h1r = fmaxf(acc1[nt][1], 0.f);
            const float h2r = fmaxf(acc1[nt][2], 0.f), h3r = fmaxf(acc1[nt][3], 0.f);
            o0 = fmaf(h0r, wa.x, fmaf(h1r, wa.y, fmaf(h2r, wa.z, fmaf(h3r, wa.w, o0))));
            o1 = fmaf(h0r, wb.x, fmaf(h1r, wb.y, fmaf(h2r, wb.z, fmaf(h3r, wb.w, o1))));
            o2 = fmaf(h0r, wc.x, fmaf(h1r, wc.y, fmaf(h2r, wc.z, fmaf(h3r, wc.w, o2))));
        }
        o0 += __shfl_xor(o0, 16); o0 += __shfl_xor(o0, 32);
        o1 += __shfl_xor(o1, 16); o1 += __shfl_xor(o1, 32);
        o2 += __shfl_xor(o2, 16); o2 += __shfl_xor(o2, 32);

        if (lane < 16) {
            const int p = blockBase + wave * 64 + t * 16 + lane;
            out[p] = o0;
            out[NPTS + p] = o1;
            out[2 * NPTS + p] = o2;
        }
    }
}

extern "C" void kernel_launch(void* const* d_in, const int* in_sizes, int n_in,
                              void* d_out, int out_size, void* d_ws, size_t ws_size,
                              hipStream_t stream) {
    const float* xy     = (const float*)d_in[0];
    const float* tables = (const float*)d_in[1];
    const float* W0     = (const float*)d_in[2];
    const float* W1     = (const float*)d_in[3];
    const float* W2     = (const float*)d_in[4];
    float* out = (float*)d_out;
    uint4* ws  = (uint4*)d_ws;   // 1536 x 16B = 24 KB

    hipLaunchKernelGGL(prep_weights, dim3(1), dim3(256), 0, stream, W0, W1, ws);
    hipLaunchKernelGGL(ngp_mfma, dim3(NPTS / 256), dim3(256), 0, stream,
                       xy, tables, W2, ws, out);
}

// Round 3
// 329.229 us; speedup vs baseline: 1.3220x; 1.3220x over previous
//
#include <hip/hip_runtime.h>
#include <cstdint>
#include <cstddef>

#define S_DIM 1024
#define NPTS (S_DIM * S_DIM)
#define NLEV 16
#define TBL (1u << 19)
#define TMASK (TBL - 1u)
#define PRIME_Y 2654435761u

typedef float v4f __attribute__((ext_vector_type(4)));
typedef short v8s __attribute__((ext_vector_type(8)));

// ---- split-bf16 helpers: x = hi + lo, both truncated bf16 ----
// pack two fp32 (a=even k, b=odd k) into one dword of 2 bf16 (a in low short).
__device__ __forceinline__ void split2(float a, float b, uint32_t& hi, uint32_t& lo) {
    uint32_t ua = __float_as_uint(a), ub = __float_as_uint(b);
    uint32_t ha = ua & 0xFFFF0000u, hb = ub & 0xFFFF0000u;
    float la = a - __uint_as_float(ha);
    float lb = b - __uint_as_float(hb);
    hi = (ha >> 16) | hb;
    lo = (__float_as_uint(la) >> 16) | (__float_as_uint(lb) & 0xFFFF0000u);
}

// ============================================================================
// Pre-pass: build bf16 hi/lo A-fragments of W0^T (64x32) and W1^T (64x64) in
// d_ws, fragment-linear so the main kernel loads each lane's 16B with one
// coalesced uint4 load.  A-frag (16x16x32): lane holds A[m=lane&15][k=q*8+j].
// ws as uint4: [0,256) W0hi | [256,512) W0lo | [512,1024) W1hi | [1024,1536) W1lo
// ============================================================================
__global__ __launch_bounds__(256) void prep_weights(const float* __restrict__ W0,
                                                    const float* __restrict__ W1,
                                                    uint4* __restrict__ ws) {
    const int tid = threadIdx.x;          // 0..255
    const int lane = tid & 63;
    const int m = lane & 15, q = lane >> 4;

    {   // W0^T: 4 n-tiles, 1 k-step. unit = tile*64+lane = tid.
        const int tile = tid >> 6;
        const int n = tile * 16 + m;
        uint32_t hi[4], lo[4];
        #pragma unroll
        for (int d = 0; d < 4; ++d) {
            const int k0 = q * 8 + 2 * d;
            split2(W0[k0 * 64 + n], W0[(k0 + 1) * 64 + n], hi[d], lo[d]);
        }
        ws[tid]       = make_uint4(hi[0], hi[1], hi[2], hi[3]);
        ws[256 + tid] = make_uint4(lo[0], lo[1], lo[2], lo[3]);
    }

    #pragma unroll
    for (int rep = 0; rep < 2; ++rep) {   // W1^T: 8 frags (nt*2+ks) x 64 lanes
        const int unit = tid + rep * 256;     // 0..511
        const int l2 = unit & 63, frag = unit >> 6;
        const int nt = frag >> 1, ks = frag & 1;
        const int mm = l2 & 15, qq = l2 >> 4;
        const int n = nt * 16 + mm;
        uint32_t hi[4], lo[4];
        #pragma unroll
        for (int d = 0; d < 4; ++d) {
            const int k0 = ks * 32 + qq * 8 + 2 * d;
            split2(W1[k0 * 64 + n], W1[(k0 + 1) * 64 + n], hi[d], lo[d]);
        }
        ws[512 + unit]  = make_uint4(hi[0], hi[1], hi[2], hi[3]);
        ws[1024 + unit] = make_uint4(lo[0], lo[1], lo[2], lo[3]);
    }
}

// ---- per-level hash-grid feature (unchanged, verified) ----
static __device__ __forceinline__ float2 level_feat(float x, float y, int res,
                                                    const float* __restrict__ tb) {
    const float fr = (float)res;
    const float px = x * fr, py = y * fr;
    const float fx = floorf(px), fy = floorf(py);
    const float wx = px - fx, wy = py - fy;
    const int x0 = (int)fx, y0 = (int)fy;

    int i00, i01, i10, i11;
    const bool dense = ((long long)(res + 1) * (long long)(res + 1) <= (long long)TBL);
    if (dense) {
        const int st = res + 1;
        i00 = x0 + y0 * st;
        i01 = i00 + st;
        i10 = i00 + 1;
        i11 = i01 + 1;
    } else {
        const unsigned a = (unsigned)x0, b = (unsigned)y0;
        const unsigned hb0 = b * PRIME_Y;
        const unsigned hb1 = (b + 1u) * PRIME_Y;
        i00 = (int)((a ^ hb0) & TMASK);
        i01 = (int)((a ^ hb1) & TMASK);
        i10 = (int)(((a + 1u) ^ hb0) & TMASK);
        i11 = (int)(((a + 1u) ^ hb1) & TMASK);
    }

    const float2 f00 = *(const float2*)(tb + 2 * (size_t)i00);
    const float2 f01 = *(const float2*)(tb + 2 * (size_t)i01);
    const float2 f10 = *(const float2*)(tb + 2 * (size_t)i10);
    const float2 f11 = *(const float2*)(tb + 2 * (size_t)i11);

    const float omx = 1.f - wx, omy = 1.f - wy;
    const float w00 = omx * omy, w01 = omx * wy, w10 = wx * omy, w11 = wx * wy;

    float2 e;
    e.x = f00.x * w00 + f01.x * w01 + f10.x * w10 + f11.x * w11;
    e.y = f00.y * w00 + f01.y * w01 + f10.y * w10 + f11.y * w11;
    return e;
}

// ============================================================================
// Main kernel. Block = 256 = 4 waves; each wave owns 64 points (4 M-tiles).
// Per M-tile (fused, #pragma unroll 1 to bound register pressure):
//   TRANSPOSED encode: lane (m,q) encodes levels 4q..4q+3 of point t*16+m ->
//     results land directly in MFMA B-frag layout (no enc LDS, no transpose).
//   L0 MFMA (A=W0^T frags from LDS), relu+split via wave-local LDS bounce,
//   L1 MFMA (A=W1^T frags from LDS), L2 (64->3) in VALU + shfl_xor reduce.
// Register budget (rounds 1-2 lesson): launch_bounds(256,4)'s 128-reg cap
// forced scratch spill (64 arch VGPR split; 1.2 GB of scratch traffic).
// Now BOTH weight layers' A-frags live in LDS (persistent reg state ~20),
// and launch_bounds(256,3) gives a 170-reg cap with ~40 regs of slack over
// the gather-phase peak (~110-130).  LDS: w0 8192 + w1 16384 + h0 17408 +
// w2t 768 + res 64 = 42.8 KB -> 3 blocks/CU = 12 waves/CU (vs round-0's 8).
// ============================================================================
__global__ __launch_bounds__(256, 3) void ngp_mfma(
    const float* __restrict__ xy,
    const float* __restrict__ tables,
    const float* __restrict__ W2,
    const uint4* __restrict__ ws,
    float* __restrict__ out)
{
    // W0^T fragments: [0,256) hi, [256,512) lo, lane-linear 16B units
    __shared__ alignas(16) uint4 w0LDS[512];                 //  8192 B
    // W1^T fragments: [0,512) hi, [512,1024) lo, lane-linear 16B units
    __shared__ alignas(16) uint4 w1LDS[1024];                // 16384 B
    // h0 rows: per wave 16 points x (64 hi | 64 lo) = 256B, padded to 272B
    __shared__ alignas(16) uint32_t h0LDS[4 * 16 * 68];      // 17408 B
    // W2 transposed: w2t[c][n], c<3, n<64 -> 16B-aligned 4-float reads
    __shared__ alignas(16) float w2t[3 * 64];                //   768 B
    __shared__ alignas(16) int resLDS[16];                   //    64 B

    const int tid = threadIdx.x;
    const int lane = tid & 63;
    const int wave = tid >> 6;
    const int m = lane & 15, q = lane >> 4;
    const int blockBase = blockIdx.x * 256;

    if (tid < 192) w2t[(tid % 3) * 64 + (tid / 3)] = W2[tid];
    if (tid < 16) {
        constexpr int RES[NLEV] = {16, 24, 36, 54, 81, 121, 182, 273,
                                   410, 615, 922, 1383, 2075, 3113, 4670, 7006};
        resLDS[tid] = RES[tid];
    }
    // stage W0+W1 frags global->LDS (1536 uint4, 6 per thread)
    #pragma unroll
    for (int i = 0; i < 2; ++i) w0LDS[tid + 256 * i] = ws[tid + 256 * i];
    #pragma unroll
    for (int i = 0; i < 4; ++i) w1LDS[tid + 256 * i] = ws[512 + tid + 256 * i];

    __syncthreads();   // w2t / resLDS / w0LDS / w1LDS visibility

    // per-q level slice: levels 4q..4q+3 -> enc dims k = 8q..8q+7
    const int4 rq = *((const int4*)(resLDS + 4 * q));
    const float* tb0 = tables + (size_t)(4 * q) * (size_t)(TBL * 2u);
    const int rr[4] = {rq.x, rq.y, rq.z, rq.w};

    uint32_t* hrow = h0LDS + (wave * 16 + m) * 68;

    // ---------------- fused per-tile loop: encode -> L0 -> L1 -> L2 --------
    #pragma unroll 1
    for (int t = 0; t < 4; ++t) {
        // ---- transposed encode: this tile's B-frag directly in registers --
        const int pid = blockBase + wave * 64 + t * 16 + m;
        const float2 p = ((const float2*)xy)[pid];
        float ef[8];
        #pragma unroll
        for (int i = 0; i < 4; ++i) {
            const float2 e = level_feat(p.x, p.y, rr[i],
                                        tb0 + (size_t)i * (size_t)(TBL * 2u));
            ef[2 * i]     = e.x;
            ef[2 * i + 1] = e.y;
        }
        uint32_t hi[4], lo[4];
        #pragma unroll
        for (int d = 0; d < 4; ++d) split2(ef[2 * d], ef[2 * d + 1], hi[d], lo[d]);
        const v8s eH = __builtin_bit_cast(v8s, make_uint4(hi[0], hi[1], hi[2], hi[3]));
        const v8s eL = __builtin_bit_cast(v8s, make_uint4(lo[0], lo[1], lo[2], lo[3]));

        // ---- L0: D0[n][p] = W0^T x enc^T, 3-term split, A-frags from LDS --
        v4f acc0[4];
        #pragma unroll
        for (int nt = 0; nt < 4; ++nt) {
            const v8s w0h = __builtin_bit_cast(v8s, w0LDS[nt * 64 + lane]);
            const v8s w0l = __builtin_bit_cast(v8s, w0LDS[256 + nt * 64 + lane]);
            v4f c = {0.f, 0.f, 0.f, 0.f};
            c = __builtin_amdgcn_mfma_f32_16x16x32_bf16(w0l, eH, c, 0, 0, 0);
            c = __builtin_amdgcn_mfma_f32_16x16x32_bf16(w0h, eL, c, 0, 0, 0);
            c = __builtin_amdgcn_mfma_f32_16x16x32_bf16(w0h, eH, c, 0, 0, 0);
            acc0[nt] = c;
        }

        // ---- relu + split h0 -> wave-local LDS bounce (C-layout -> B-layout)
        // lane holds h0[n = nt*16 + q*4 + r][p = m]
        #pragma unroll
        for (int nt = 0; nt < 4; ++nt) {
            const float r0 = fmaxf(acc0[nt][0], 0.f), r1 = fmaxf(acc0[nt][1], 0.f);
            const float r2 = fmaxf(acc0[nt][2], 0.f), r3 = fmaxf(acc0[nt][3], 0.f);
            uint32_t h0w, l0w, h1w, l1w;
            split2(r0, r1, h0w, l0w);
            split2(r2, r3, h1w, l1w);
            *((uint2*)(hrow + nt * 8 + q * 2))      = make_uint2(h0w, h1w);
            *((uint2*)(hrow + 32 + nt * 8 + q * 2)) = make_uint2(l0w, l1w);
        }

        // ---- L1 B-frags (k = ks*32 + q*8 + j for point m) ----
        const v8s b0H = __builtin_bit_cast(v8s, *((const uint4*)(hrow + q * 4)));
        const v8s b0L = __builtin_bit_cast(v8s, *((const uint4*)(hrow + 32 + q * 4)));
        const v8s b1H = __builtin_bit_cast(v8s, *((const uint4*)(hrow + 16 + q * 4)));
        const v8s b1L = __builtin_bit_cast(v8s, *((const uint4*)(hrow + 48 + q * 4)));

        // ---- L1: D1[n][p] = W1^T x h0^T, A-frags streamed from LDS ----
        v4f acc1[4];
        #pragma unroll
        for (int nt = 0; nt < 4; ++nt) {
            const v8s a0h = __builtin_bit_cast(v8s, w1LDS[(nt * 2 + 0) * 64 + lane]);
            const v8s a0l = __builtin_bit_cast(v8s, w1LDS[512 + (nt * 2 + 0) * 64 + lane]);
            const v8s a1h = __builtin_bit_cast(v8s, w1LDS[(nt * 2 + 1) * 64 + lane]);
            const v8s a1l = __builtin_bit_cast(v8s, w1LDS[512 + (nt * 2 + 1) * 64 + lane]);
            v4f c = {0.f, 0.f, 0.f, 0.f};
            c = __builtin_amdgcn_mfma_f32_16x16x32_bf16(a0l, b0H, c, 0, 0, 0);
            c = __builtin_amdgcn_mfma_f32_16x16x32_bf16(a0h, b0L, c, 0, 0, 0);
            c = __builtin_amdgcn_mfma_f32_16x16x32_bf16(a0h, b0H, c, 0, 0, 0);
            c = __builtin_amdgcn_mfma_f32_16x16x32_bf16(a1l, b1H, c, 0, 0, 0);
            c = __builtin_amdgcn_mfma_f32_16x16x32_bf16(a1h, b1L, c, 0, 0, 0);
            c = __builtin_amdgcn_mfma_f32_16x16x32_bf16(a1h, b1H, c, 0, 0, 0);
            acc1[nt] = c;
        }

        // ---- L2 (64->3) in VALU: lane sums its 16 n's, quad-reduce ----
        float o0 = 0.f, o1 = 0.f, o2 = 0.f;
        #pragma unroll
        for (int nt = 0; nt < 4; ++nt) {
            const int n = nt * 16 + q * 4;
            const float4 wa = *((const float4*)(w2t + 0 * 64 + n));
            const float4 wb = *((const float4*)(w2t + 1 * 64 + n));
            const float4 wc = *((const float4*)(w2t + 2 * 64 + n));
            const float h0r = fmaxf(acc1[nt][0], 0.f), h1r = fmaxf(acc1[nt][1], 0.f);
            const float h2r = fmaxf(acc1[nt][2], 0.f), h3r = fmaxf(acc1[nt][3], 0.f);
            o0 = fmaf(h0r, wa.x, fmaf(h1r, wa.y, fmaf(h2r, wa.z, fmaf(h3r, wa.w, o0))));
            o1 = fmaf(h0r, wb.x, fmaf(h1r, wb.y, fmaf(h2r, wb.z, fmaf(h3r, wb.w, o1))));
            o2 = fmaf(h0r, wc.x, fmaf(h1r, wc.y, fmaf(h2r, wc.z, fmaf(h3r, wc.w, o2))));
        }
        o0 += __shfl_xor(o0, 16); o0 += __shfl_xor(o0, 32);
        o1 += __shfl_xor(o1, 16); o1 += __shfl_xor(o1, 32);
        o2 += __shfl_xor(o2, 16); o2 += __shfl_xor(o2, 32);

        if (lane < 16) {
            const int p = blockBase + wave * 64 + t * 16 + lane;
            out[p] = o0;
            out[NPTS + p] = o1;
            out[2 * NPTS + p] = o2;
        }
    }
}

extern "C" void kernel_launch(void* const* d_in, const int* in_sizes, int n_in,
                              void* d_out, int out_size, void* d_ws, size_t ws_size,
                              hipStream_t stream) {
    const float* xy     = (const float*)d_in[0];
    const float* tables = (const float*)d_in[1];
    const float* W0     = (const float*)d_in[2];
    const float* W1     = (const float*)d_in[3];
    const float* W2     = (const float*)d_in[4];
    float* out = (float*)d_out;
    uint4* ws  = (uint4*)d_ws;   // 1536 x 16B = 24 KB

    hipLaunchKernelGGL(prep_weights, dim3(1), dim3(256), 0, stream, W0, W1, ws);
    hipLaunchKernelGGL(ngp_mfma, dim3(NPTS / 256), dim3(256), 0, stream,
                       xy, tables, W2, ws, out);
}

// Round 4
// 200.906 us; speedup vs baseline: 2.1664x; 1.6387x over previous
//
#include <hip/hip_runtime.h>
#include <cstdint>
#include <cstddef>

#define S_DIM 1024
#define NPTS (S_DIM * S_DIM)
#define NLEV 16
#define TBL (1u << 19)
#define TMASK (TBL - 1u)
#define PRIME_Y 2654435761u

typedef float v4f __attribute__((ext_vector_type(4)));
typedef short v8s __attribute__((ext_vector_type(8)));

// ---- split-bf16 helpers: x = hi + lo, both truncated bf16 ----
// pack two fp32 (a=even k, b=odd k) into one dword of 2 bf16 (a in low short).
__device__ __forceinline__ void split2(float a, float b, uint32_t& hi, uint32_t& lo) {
    uint32_t ua = __float_as_uint(a), ub = __float_as_uint(b);
    uint32_t ha = ua & 0xFFFF0000u, hb = ub & 0xFFFF0000u;
    float la = a - __uint_as_float(ha);
    float lb = b - __uint_as_float(hb);
    hi = (ha >> 16) | hb;
    lo = (__float_as_uint(la) >> 16) | (__float_as_uint(lb) & 0xFFFF0000u);
}

// ============================================================================
// Pre-pass: build bf16 hi/lo A-fragments of W0^T (64x32) and W1^T (64x64) in
// d_ws, fragment-linear so the main kernel loads each lane's 16B with one
// coalesced uint4 load.  A-frag (16x16x32): lane holds A[m=lane&15][k=q*8+j].
// ws as uint4: [0,256) W0hi | [256,512) W0lo | [512,1024) W1hi | [1024,1536) W1lo
// ============================================================================
__global__ __launch_bounds__(256) void prep_weights(const float* __restrict__ W0,
                                                    const float* __restrict__ W1,
                                                    uint4* __restrict__ ws) {
    const int tid = threadIdx.x;          // 0..255
    const int lane = tid & 63;
    const int m = lane & 15, q = lane >> 4;

    {   // W0^T: 4 n-tiles, 1 k-step. unit = tile*64+lane = tid.
        const int tile = tid >> 6;
        const int n = tile * 16 + m;
        uint32_t hi[4], lo[4];
        #pragma unroll
        for (int d = 0; d < 4; ++d) {
            const int k0 = q * 8 + 2 * d;
            split2(W0[k0 * 64 + n], W0[(k0 + 1) * 64 + n], hi[d], lo[d]);
        }
        ws[tid]       = make_uint4(hi[0], hi[1], hi[2], hi[3]);
        ws[256 + tid] = make_uint4(lo[0], lo[1], lo[2], lo[3]);
    }

    #pragma unroll
    for (int rep = 0; rep < 2; ++rep) {   // W1^T: 8 frags (nt*2+ks) x 64 lanes
        const int unit = tid + rep * 256;     // 0..511
        const int l2 = unit & 63, frag = unit >> 6;
        const int nt = frag >> 1, ks = frag & 1;
        const int mm = l2 & 15, qq = l2 >> 4;
        const int n = nt * 16 + mm;
        uint32_t hi[4], lo[4];
        #pragma unroll
        for (int d = 0; d < 4; ++d) {
            const int k0 = ks * 32 + qq * 8 + 2 * d;
            split2(W1[k0 * 64 + n], W1[(k0 + 1) * 64 + n], hi[d], lo[d]);
        }
        ws[512 + unit]  = make_uint4(hi[0], hi[1], hi[2], hi[3]);
        ws[1024 + unit] = make_uint4(lo[0], lo[1], lo[2], lo[3]);
    }
}

// ---- per-level hash-grid feature (unchanged, verified all rounds) ----
static __device__ __forceinline__ float2 level_feat(float x, float y, int res,
                                                    const float* __restrict__ tb) {
    const float fr = (float)res;
    const float px = x * fr, py = y * fr;
    const float fx = floorf(px), fy = floorf(py);
    const float wx = px - fx, wy = py - fy;
    const int x0 = (int)fx, y0 = (int)fy;

    int i00, i01, i10, i11;
    const bool dense = ((long long)(res + 1) * (long long)(res + 1) <= (long long)TBL);
    if (dense) {
        const int st = res + 1;
        i00 = x0 + y0 * st;
        i01 = i00 + st;
        i10 = i00 + 1;
        i11 = i01 + 1;
    } else {
        const unsigned a = (unsigned)x0, b = (unsigned)y0;
        const unsigned hb0 = b * PRIME_Y;
        const unsigned hb1 = (b + 1u) * PRIME_Y;
        i00 = (int)((a ^ hb0) & TMASK);
        i01 = (int)((a ^ hb1) & TMASK);
        i10 = (int)(((a + 1u) ^ hb0) & TMASK);
        i11 = (int)(((a + 1u) ^ hb1) & TMASK);
    }

    const float2 f00 = *(const float2*)(tb + 2 * (size_t)i00);
    const float2 f01 = *(const float2*)(tb + 2 * (size_t)i01);
    const float2 f10 = *(const float2*)(tb + 2 * (size_t)i10);
    const float2 f11 = *(const float2*)(tb + 2 * (size_t)i11);

    const float omx = 1.f - wx, omy = 1.f - wy;
    const float w00 = omx * omy, w01 = omx * wy, w10 = wx * omy, w11 = wx * wy;

    float2 e;
    e.x = f00.x * w00 + f01.x * w01 + f10.x * w10 + f11.x * w11;
    e.y = f00.y * w00 + f01.y * w01 + f10.y * w10 + f11.y * w11;
    return e;
}

// ============================================================================
// Main kernel. Round-0 structure (per-point encode, proven spill-free at
// VGPR=92) with the LDS footprint cut from 55 KB -> 53 KB so 3 blocks/CU fit:
//   - w2t LDS eliminated: W2 (768 B, L1-resident) read directly per nt-step
//     as 3 contiguous float4 + register shuffle.
//   - W1 fragments NOT register/AGPR-resident (round-0 put 64 regs of W1 in
//     the unified file, near the cap): streamed per tile from ws (24 KB,
//     L1-resident).  W0 frags stay in registers (32).
//   - no __syncthreads at all: encLDS/h0LDS are wave-local.
// Rounds 1-3 lesson: the transposed encode's 16-gather burst + unified
// VGPR/AGPR split forced scratch spill (200+ MB) at every cap tried.  The
// per-point encode here peaks lower and is verified spill-free.
// LDS: enc 36864 + h0 17408 = 54272 <= 163840/3 -> 3 blocks/CU, 12 waves/CU.
// ============================================================================
__global__ __launch_bounds__(256, 3) void ngp_mfma(
    const float* __restrict__ xy,
    const float* __restrict__ tables,
    const float* __restrict__ W2,
    const uint4* __restrict__ ws,
    float* __restrict__ out)
{
    // enc rows: 256 points x (16 hi | 16 lo dwords) = 128B, padded to 144B
    __shared__ alignas(16) uint32_t encLDS[256 * 36];        // 36864 B
    // h0 rows: per wave 16 points x (64 hi | 64 lo) = 256B, padded to 272B
    __shared__ alignas(16) uint32_t h0LDS[4 * 16 * 68];      // 17408 B

    const int tid = threadIdx.x;
    const int lane = tid & 63;
    const int wave = tid >> 6;
    const int m = lane & 15, q = lane >> 4;
    const int blockBase = blockIdx.x * 256;

    // ---------------- Phase 1: encode own point ----------------
    {
        const int pid = blockBase + tid;
        const float2 p = ((const float2*)xy)[pid];
        constexpr int RES[NLEV] = {16, 24, 36, 54, 81, 121, 182, 273,
                                   410, 615, 922, 1383, 2075, 3113, 4670, 7006};
        float enc[32];
        #pragma unroll
        for (int l = 0; l < NLEV; ++l) {
            const float* tb = tables + (size_t)l * (size_t)(TBL * 2u);
            const float2 e = level_feat(p.x, p.y, RES[l], tb);
            enc[2 * l] = e.x;
            enc[2 * l + 1] = e.y;
        }
        uint32_t hi[16], lo[16];
        #pragma unroll
        for (int d = 0; d < 16; ++d) split2(enc[2 * d], enc[2 * d + 1], hi[d], lo[d]);
        uint32_t* row = encLDS + tid * 36;
        #pragma unroll
        for (int i = 0; i < 4; ++i) {
            *((uint4*)(row + 4 * i))      = make_uint4(hi[4*i], hi[4*i+1], hi[4*i+2], hi[4*i+3]);
            *((uint4*)(row + 16 + 4 * i)) = make_uint4(lo[4*i], lo[4*i+1], lo[4*i+2], lo[4*i+3]);
        }
    }
    // NO __syncthreads: encLDS and h0LDS are wave-local (each wave reads only
    // rows it wrote; in-wave LDS ordering is handled by the compiler's waits).

    // ---------------- W0 fragments: registers, reused by all 4 tiles -------
    v8s w0h[4], w0l[4];
    #pragma unroll
    for (int t = 0; t < 4; ++t) {
        w0h[t] = __builtin_bit_cast(v8s, ws[t * 64 + lane]);
        w0l[t] = __builtin_bit_cast(v8s, ws[256 + t * 64 + lane]);
    }

    uint32_t* hrow = h0LDS + (wave * 16 + m) * 68;

    // ---------------- Phase 2: 4 M-tiles of 16 points ----------------
    #pragma unroll 1
    for (int t = 0; t < 4; ++t) {
        // launder a zero offset through an opaque asm so LICM cannot hoist
        // the per-tile W1-fragment / W2 global loads out of this loop (a
        // hoist would add ~76 live regs -> the rounds-1-3 spill disease).
        int tOff = 0;
        asm volatile("" : "+v"(tOff));

        // B-frag of enc for this tile: point p = wave*64 + t*16 + m
        const uint32_t* erow = encLDS + (wave * 64 + t * 16 + m) * 36;
        const v8s eH = __builtin_bit_cast(v8s, *((const uint4*)(erow + q * 4)));
        const v8s eL = __builtin_bit_cast(v8s, *((const uint4*)(erow + 16 + q * 4)));

        // ---- L0: D0[n][p] = W0^T x enc^T, 3-term split ----
        v4f acc0[4];
        #pragma unroll
        for (int nt = 0; nt < 4; ++nt) {
            v4f c = {0.f, 0.f, 0.f, 0.f};
            c = __builtin_amdgcn_mfma_f32_16x16x32_bf16(w0l[nt], eH, c, 0, 0, 0);
            c = __builtin_amdgcn_mfma_f32_16x16x32_bf16(w0h[nt], eL, c, 0, 0, 0);
            c = __builtin_amdgcn_mfma_f32_16x16x32_bf16(w0h[nt], eH, c, 0, 0, 0);
            acc0[nt] = c;
        }

        // ---- relu + split h0 -> wave-local LDS bounce (C-layout -> B-layout)
        // lane holds h0[n = nt*16 + q*4 + r][p = m]
        #pragma unroll
        for (int nt = 0; nt < 4; ++nt) {
            const float r0 = fmaxf(acc0[nt][0], 0.f), r1 = fmaxf(acc0[nt][1], 0.f);
            const float r2 = fmaxf(acc0[nt][2], 0.f), r3 = fmaxf(acc0[nt][3], 0.f);
            uint32_t h0w, l0w, h1w, l1w;
            split2(r0, r1, h0w, l0w);
            split2(r2, r3, h1w, l1w);
            *((uint2*)(hrow + nt * 8 + q * 2))      = make_uint2(h0w, h1w);
            *((uint2*)(hrow + 32 + nt * 8 + q * 2)) = make_uint2(l0w, l1w);
        }

        // ---- L1 B-frags (k = ks*32 + q*8 + j for point m) ----
        const v8s b0H = __builtin_bit_cast(v8s, *((const uint4*)(hrow + q * 4)));
        const v8s b0L = __builtin_bit_cast(v8s, *((const uint4*)(hrow + 32 + q * 4)));
        const v8s b1H = __builtin_bit_cast(v8s, *((const uint4*)(hrow + 16 + q * 4)));
        const v8s b1L = __builtin_bit_cast(v8s, *((const uint4*)(hrow + 48 + q * 4)));

        // ---- L1: D1[n][p] = W1^T x h0^T, A-frags streamed from global (L1) -
        v4f acc1[4];
        #pragma unroll
        for (int nt = 0; nt < 4; ++nt) {
            const v8s a0h = __builtin_bit_cast(v8s, ws[512  + tOff + (nt * 2 + 0) * 64 + lane]);
            const v8s a0l = __builtin_bit_cast(v8s, ws[1024 + tOff + (nt * 2 + 0) * 64 + lane]);
            const v8s a1h = __builtin_bit_cast(v8s, ws[512  + tOff + (nt * 2 + 1) * 64 + lane]);
            const v8s a1l = __builtin_bit_cast(v8s, ws[1024 + tOff + (nt * 2 + 1) * 64 + lane]);
            v4f c = {0.f, 0.f, 0.f, 0.f};
            c = __builtin_amdgcn_mfma_f32_16x16x32_bf16(a0l, b0H, c, 0, 0, 0);
            c = __builtin_amdgcn_mfma_f32_16x16x32_bf16(a0h, b0L, c, 0, 0, 0);
            c = __builtin_amdgcn_mfma_f32_16x16x32_bf16(a0h, b0H, c, 0, 0, 0);
            c = __builtin_amdgcn_mfma_f32_16x16x32_bf16(a1l, b1H, c, 0, 0, 0);
            c = __builtin_amdgcn_mfma_f32_16x16x32_bf16(a1h, b1L, c, 0, 0, 0);
            c = __builtin_amdgcn_mfma_f32_16x16x32_bf16(a1h, b1H, c, 0, 0, 0);
            acc1[nt] = c;
        }

        // ---- L2 (64->3) in VALU: W2 read直接 from global (768 B, L1-hot).
        // W2 layout [n][c]: lane needs rows n0..n0+3 = 12 contiguous floats
        // at W2 + n0*3 (48B-aligned). Shuffle to per-channel quads in regs.
        float o0 = 0.f, o1 = 0.f, o2 = 0.f;
        #pragma unroll
        for (int nt = 0; nt < 4; ++nt) {
            const int n0 = nt * 16 + q * 4;
            const float4 g0 = *((const float4*)(W2 + n0 * 3 + tOff));
            const float4 g1 = *((const float4*)(W2 + n0 * 3 + tOff + 4));
            const float4 g2 = *((const float4*)(W2 + n0 * 3 + tOff + 8));
            const float h0r = fmaxf(acc1[nt][0], 0.f), h1r = fmaxf(acc1[nt][1], 0.f);
            const float h2r = fmaxf(acc1[nt][2], 0.f), h3r = fmaxf(acc1[nt][3], 0.f);
            o0 = fmaf(h0r, g0.x, fmaf(h1r, g0.w, fmaf(h2r, g1.z, fmaf(h3r, g2.y, o0))));
            o1 = fmaf(h0r, g0.y, fmaf(h1r, g1.x, fmaf(h2r, g1.w, fmaf(h3r, g2.z, o1))));
            o2 = fmaf(h0r, g0.z, fmaf(h1r, g1.y, fmaf(h2r, g2.x, fmaf(h3r, g2.w, o2))));
        }
        o0 += __shfl_xor(o0, 16); o0 += __shfl_xor(o0, 32);
        o1 += __shfl_xor(o1, 16); o1 += __shfl_xor(o1, 32);
        o2 += __shfl_xor(o2, 16); o2 += __shfl_xor(o2, 32);

        if (lane < 16) {
            const int p = blockBase + wave * 64 + t * 16 + lane;
            out[p] = o0;
            out[NPTS + p] = o1;
            out[2 * NPTS + p] = o2;
        }
    }
}

extern "C" void kernel_launch(void* const* d_in, const int* in_sizes, int n_in,
                              void* d_out, int out_size, void* d_ws, size_t ws_size,
                              hipStream_t stream) {
    const float* xy     = (const float*)d_in[0];
    const float* tables = (const float*)d_in[1];
    const float* W0     = (const float*)d_in[2];
    const float* W1     = (const float*)d_in[3];
    const float* W2     = (const float*)d_in[4];
    float* out = (float*)d_out;
    uint4* ws  = (uint4*)d_ws;   // 1536 x 16B = 24 KB

    hipLaunchKernelGGL(prep_weights, dim3(1), dim3(256), 0, stream, W0, W1, ws);
    hipLaunchKernelGGL(ngp_mfma, dim3(NPTS / 256), dim3(256), 0, stream,
                       xy, tables, W2, ws, out);
}